// Round 3
// baseline (2196.516 us; speedup 1.0000x reference)
//
#include <hip/hip_runtime.h>

#define NN 50000
#define EE 1000000

__device__ __forceinline__ float wsum(float v){
#pragma unroll
  for(int m=1;m<64;m<<=1) v += __shfl_xor(v,m,64);
  return v;
}
__device__ __forceinline__ float wmax(float v){
#pragma unroll
  for(int m=1;m<64;m<<=1) v = fmaxf(v,__shfl_xor(v,m,64));
  return v;
}

// ---------------- zero counts/cursor/h2f ----------------
__global__ __launch_bounds__(256) void zero_k(int* counts, int* cursor, float* h2f){
  int i = blockIdx.x*blockDim.x + threadIdx.x;
  if(i < NN*64) h2f[i] = 0.0f;
  if(i < NN){ counts[i] = 0; cursor[i] = 0; }
}

// ---------------- node MLP: x = relu(LN(X@w + b)) ----------------
__global__ __launch_bounds__(256) void node_mlp(const float* __restrict__ X, const float* __restrict__ w,
                                                const float* __restrict__ b, const float* __restrict__ g,
                                                const float* __restrict__ beta, float* __restrict__ x){
  int wid  = (blockIdx.x*blockDim.x + threadIdx.x) >> 6;
  int lane = threadIdx.x & 63;
  if(wid >= NN) return;
  float acc = b[lane];
#pragma unroll
  for(int k=0;k<16;k++) acc += X[wid*16+k] * w[k*64+lane];
  float mu  = wsum(acc) * (1.0f/64.0f);
  float d   = acc - mu;
  float var = wsum(d*d) * (1.0f/64.0f);
  float y   = d * rsqrtf(var + 1e-5f) * g[lane] + beta[lane];
  x[(size_t)wid*64 + lane] = fmaxf(y, 0.0f);
}

// ---------------- edge MLP + 9 a_edge dots: q[r][e] ----------------
__global__ __launch_bounds__(256) void edge_mlp_q(const float* __restrict__ ea, const float* __restrict__ w,
                                                  const float* __restrict__ b, const float* __restrict__ g,
                                                  const float* __restrict__ beta, const float* __restrict__ gat_a,
                                                  const float* __restrict__ out_a, float* __restrict__ q){
  int e = blockIdx.x*blockDim.x + threadIdx.x;
  if(e >= EE) return;
  float in[8];
#pragma unroll
  for(int k=0;k<8;k++) in[k] = ea[(size_t)e*8 + k];
  float y[64];
#pragma unroll
  for(int j=0;j<64;j++){
    float acc = b[j];
#pragma unroll
    for(int k=0;k<8;k++) acc += in[k] * w[k*64+j];
    y[j] = acc;
  }
  float mu = 0.f;
#pragma unroll
  for(int j=0;j<64;j++) mu += y[j];
  mu *= (1.0f/64.0f);
  float var = 0.f;
#pragma unroll
  for(int j=0;j<64;j++){ float d = y[j]-mu; var += d*d; }
  var *= (1.0f/64.0f);
  float inv = rsqrtf(var + 1e-5f);
#pragma unroll
  for(int j=0;j<64;j++) y[j] = fmaxf((y[j]-mu)*inv*g[j] + beta[j], 0.0f);
#pragma unroll
  for(int r=0;r<9;r++){
    const float* av = (r<8) ? (gat_a + r*192 + 128) : (out_a + 128);
    float d = 0.f;
#pragma unroll
    for(int j=0;j<64;j++) d += y[j]*av[j];
    q[(size_t)r*EE + e] = d;
  }
}

// ---------------- CSR build ----------------
__global__ __launch_bounds__(256) void hist_k(const int* __restrict__ src, int* __restrict__ counts){
  int e = blockIdx.x*blockDim.x + threadIdx.x;
  if(e < EE){
    int s = src[e];
    if((unsigned)s >= NN) s = 0;   // defensive clamp (finite-wrong beats NaN)
    atomicAdd(&counts[s], 1);
  }
}

__global__ __launch_bounds__(1024) void scan_k(const int* __restrict__ counts, int* __restrict__ offs){
  const int T = 1024;
  int t = threadIdx.x;
  int chunk = (NN + T - 1) / T;
  int lo = t*chunk;
  int hi = lo + chunk; if(hi > NN) hi = NN;
  int s = 0;
  for(int i=lo;i<hi;i++) s += counts[i];
  __shared__ int sm[T];
  sm[t] = s; __syncthreads();
  for(int off=1; off<T; off<<=1){
    int v = (t >= off) ? sm[t-off] : 0;
    __syncthreads();
    sm[t] += v;
    __syncthreads();
  }
  int run = sm[t] - s;             // exclusive prefix of this thread's chunk
  for(int i=lo;i<hi;i++){ offs[i] = run; run += counts[i]; }
  if(t == T-1) offs[NN] = run;     // == EE
}

__global__ __launch_bounds__(256) void scatter_k(const int* __restrict__ src, const int* __restrict__ offs,
                                                 int* __restrict__ cursor, int* __restrict__ perm){
  int e = blockIdx.x*blockDim.x + threadIdx.x;
  if(e < EE){
    int s = src[e];
    if((unsigned)s >= NN) s = 0;   // same clamp as hist_k -> consistent CSR
    int pos = offs[s] + atomicAdd(&cursor[s], 1);
    perm[pos] = e;
  }
}

// ---------------- per-head projection: H = x@W, p_src, p_tgt ----------------
__global__ __launch_bounds__(256) void project(const float* __restrict__ x, const float* __restrict__ W,
                                               const float* __restrict__ a, float* __restrict__ H,
                                               float* __restrict__ psrc, float* __restrict__ ptgt){
  int wid  = (blockIdx.x*blockDim.x + threadIdx.x) >> 6;
  int lane = threadIdx.x & 63;
  if(wid >= NN) return;
  float xv = x[(size_t)wid*64 + lane];
  float acc = 0.f;
#pragma unroll
  for(int k=0;k<64;k++){
    acc += __shfl(xv, k, 64) * W[k*64+lane];
  }
  H[(size_t)wid*64 + lane] = acc;
  float ps = wsum(acc * a[lane]);
  float pt = wsum(acc * a[64+lane]);
  if(lane == 0){ psrc[wid] = ps; ptgt[wid] = pt; }
}

// ---- per-head aggregation (online softmax) + fused out_W GEMV into h2f ----
__global__ __launch_bounds__(256) void aggregate_head(const int* __restrict__ offs, const int* __restrict__ perm,
                                                      const int* __restrict__ tgt, const float* __restrict__ psrc,
                                                      const float* __restrict__ ptgt, const float* __restrict__ q,
                                                      const float* __restrict__ H, const float* __restrict__ outW,
                                                      int h, float* __restrict__ h2f){
  int wid  = (blockIdx.x*blockDim.x + threadIdx.x) >> 6;
  int lane = threadIdx.x & 63;
  if(wid >= NN) return;
  int b  = offs[wid];
  int e2 = offs[wid+1];
  float ps = psrc[wid];
  float m = -3.0e38f, num = 0.f, den = 0.f;
  for(int i=b;i<e2;i++){
    int pe = perm[i];
    int t  = tgt[pe];
    if((unsigned)t >= NN) t = 0;   // defensive clamp
    float s = ps + ptgt[t] + q[pe];
    s = (s > 0.f) ? s : 0.01f*s;   // leaky_relu
    if(s > m){                     // online-softmax rescale (wave-uniform branch)
      float c = __expf(m - s);
      num *= c; den *= c; m = s;
    }
    float ev = __expf(s - m);
    den += ev;
    num += ev * H[(size_t)t*64 + lane];
  }
  float hp = (den > 0.f) ? num/den : 0.f;
  float z  = (hp > 0.f) ? hp : expm1f(hp);   // elu (gat_layer output)
  float z2 = (z  > 0.f) ? z  : expm1f(z);    // elu (xh = elu(concat))
  // fused GEMV: h2 += z2_row @ out_W[h*64:(h+1)*64, :]
  float acc = 0.f;
#pragma unroll
  for(int j=0;j<64;j++){
    float zj = __shfl(z2, j, 64);
    acc += zj * outW[(size_t)(h*64+j)*64 + lane];
  }
  h2f[(size_t)wid*64 + lane] += acc;
}

// ---- finalize: p2 from h2f, h2 (f32) written into H buffer ----
__global__ __launch_bounds__(256) void finalize_k(const float* __restrict__ h2f, const float* __restrict__ out_a,
                                                  float* __restrict__ H, float* __restrict__ psrc,
                                                  float* __restrict__ ptgt){
  int wid  = (blockIdx.x*blockDim.x + threadIdx.x) >> 6;
  int lane = threadIdx.x & 63;
  if(wid >= NN) return;
  float v = h2f[(size_t)wid*64 + lane];
  float ps = wsum(v * out_a[lane]);
  float pt = wsum(v * out_a[64+lane]);
  if(lane == 0){ psrc[wid] = ps; ptgt[wid] = pt; }
  H[(size_t)wid*64 + lane] = v;
}

// ---- output layer aggregation + log_softmax -> dout (f32) ----
__global__ __launch_bounds__(256) void aggregate_out(const int* __restrict__ offs, const int* __restrict__ perm,
                                                     const int* __restrict__ tgt, const float* __restrict__ psrc,
                                                     const float* __restrict__ ptgt, const float* __restrict__ q,
                                                     const float* __restrict__ H, float* __restrict__ dout){
  int wid  = (blockIdx.x*blockDim.x + threadIdx.x) >> 6;
  int lane = threadIdx.x & 63;
  if(wid >= NN) return;
  int b  = offs[wid];
  int e2 = offs[wid+1];
  float ps = psrc[wid];
  float m = -3.0e38f, num = 0.f, den = 0.f;
  for(int i=b;i<e2;i++){
    int pe = perm[i];
    int t  = tgt[pe];
    if((unsigned)t >= NN) t = 0;
    float s = ps + ptgt[t] + q[pe];
    s = (s > 0.f) ? s : 0.01f*s;
    if(s > m){
      float c = __expf(m - s);
      num *= c; den *= c; m = s;
    }
    float ev = __expf(s - m);
    den += ev;
    num += ev * H[(size_t)t*64 + lane];
  }
  float hp = (den > 0.f) ? num/den : 0.f;
  float z  = (hp > 0.f) ? hp : expm1f(hp);   // elu
  float mm  = wmax(z);
  float lse = mm + logf(wsum(__expf(z - mm)));
  dout[(size_t)wid*64 + lane] = z - lse;
}

extern "C" void kernel_launch(void* const* d_in, const int* in_sizes, int n_in,
                              void* d_out, int out_size, void* d_ws, size_t ws_size,
                              hipStream_t stream) {
  const float* X         = (const float*)d_in[0];
  const float* edge_attr = (const float*)d_in[1];
  const int*   edge_index= (const int*)d_in[2];
  // d_in[3] matched_car_infra_nodes: unused by reference
  const float* w_node    = (const float*)d_in[4];
  const float* b_node    = (const float*)d_in[5];
  const float* g_node    = (const float*)d_in[6];
  const float* beta_node = (const float*)d_in[7];
  const float* w_edge    = (const float*)d_in[8];
  const float* b_edge    = (const float*)d_in[9];
  const float* g_edge    = (const float*)d_in[10];
  const float* beta_edge = (const float*)d_in[11];
  const float* gat_W     = (const float*)d_in[12];
  const float* gat_a     = (const float*)d_in[13];
  const float* out_W     = (const float*)d_in[14];
  const float* out_a     = (const float*)d_in[15];
  float* dout = (float*)d_out;

  const int* src = edge_index;
  const int* tgt = edge_index + EE;

  // ---- workspace layout: control arrays first; all f32 (bytes, 16B aligned) ----
  char* base = (char*)d_ws;
  size_t off = 0;
  auto take = [&](size_t bytes)->char*{ char* p = base + off; off += (bytes + 15) & ~(size_t)15; return p; };
  int*    counts = (int*)  take((size_t)NN*4);
  int*    cursor = (int*)  take((size_t)NN*4);
  int*    offs   = (int*)  take((size_t)(NN+1)*4);
  float*  psrc   = (float*)take((size_t)NN*4);
  float*  ptgt   = (float*)take((size_t)NN*4);
  int*    perm   = (int*)  take((size_t)EE*4);
  float*  h2f    = (float*)take((size_t)NN*64*4);
  float*  x      = (float*)take((size_t)NN*64*4);
  float*  H      = (float*)take((size_t)NN*64*4);
  float*  q      = (float*)take((size_t)9*EE*4);
  // total ~79.3 MB

  const int NBLK_N  = (NN*64 + 255)/256;   // wave-per-node kernels: 12500
  const int NBLK_E  = (EE + 255)/256;      // thread-per-edge kernels: 3907

  zero_k<<<NBLK_N, 256, 0, stream>>>(counts, cursor, h2f);
  node_mlp<<<NBLK_N, 256, 0, stream>>>(X, w_node, b_node, g_node, beta_node, x);
  edge_mlp_q<<<NBLK_E, 256, 0, stream>>>(edge_attr, w_edge, b_edge, g_edge, beta_edge, gat_a, out_a, q);
  hist_k<<<NBLK_E, 256, 0, stream>>>(src, counts);
  scan_k<<<1, 1024, 0, stream>>>(counts, offs);
  scatter_k<<<NBLK_E, 256, 0, stream>>>(src, offs, cursor, perm);

  for(int h=0; h<8; h++){
    project<<<NBLK_N, 256, 0, stream>>>(x, gat_W + (size_t)h*64*64, gat_a + (size_t)h*192, H, psrc, ptgt);
    aggregate_head<<<NBLK_N, 256, 0, stream>>>(offs, perm, tgt, psrc, ptgt, q + (size_t)h*EE, H,
                                               out_W, h, h2f);
  }

  finalize_k<<<NBLK_N, 256, 0, stream>>>(h2f, out_a, H, psrc, ptgt);
  aggregate_out<<<NBLK_N, 256, 0, stream>>>(offs, perm, tgt, psrc, ptgt, q + (size_t)8*EE, H, dout);
}

// Round 4
// 1382.717 us; speedup vs baseline: 1.5886x; 1.5886x over previous
//
#include <hip/hip_runtime.h>

#define NN 50000
#define EE 1000000

__device__ __forceinline__ float wsum(float v){
#pragma unroll
  for(int m=1;m<64;m<<=1) v += __shfl_xor(v,m,64);
  return v;
}
__device__ __forceinline__ float wmax(float v){
#pragma unroll
  for(int m=1;m<64;m<<=1) v = fmaxf(v,__shfl_xor(v,m,64));
  return v;
}

// ---------------- zero counts/cursor/h2f ----------------
__global__ __launch_bounds__(256) void zero_k(int* counts, int* cursor, float* h2f){
  int i = blockIdx.x*blockDim.x + threadIdx.x;
  if(i < NN*64) h2f[i] = 0.0f;
  if(i < NN){ counts[i] = 0; cursor[i] = 0; }
}

// ---------------- node MLP: x = relu(LN(X@w + b)) ----------------
__global__ __launch_bounds__(256) void node_mlp(const float* __restrict__ X, const float* __restrict__ w,
                                                const float* __restrict__ b, const float* __restrict__ g,
                                                const float* __restrict__ beta, float* __restrict__ x){
  int wid  = (blockIdx.x*blockDim.x + threadIdx.x) >> 6;
  int lane = threadIdx.x & 63;
  if(wid >= NN) return;
  float acc = b[lane];
#pragma unroll
  for(int k=0;k<16;k++) acc += X[wid*16+k] * w[k*64+lane];
  float mu  = wsum(acc) * (1.0f/64.0f);
  float d   = acc - mu;
  float var = wsum(d*d) * (1.0f/64.0f);
  float y   = d * rsqrtf(var + 1e-5f) * g[lane] + beta[lane];
  x[(size_t)wid*64 + lane] = fmaxf(y, 0.0f);
}

// ---------------- CSR build ----------------
__global__ __launch_bounds__(256) void hist_k(const int* __restrict__ src, int* __restrict__ counts){
  int e = blockIdx.x*blockDim.x + threadIdx.x;
  if(e < EE){
    int s = src[e];
    if((unsigned)s >= NN) s = 0;
    atomicAdd(&counts[s], 1);
  }
}

__global__ __launch_bounds__(1024) void scan_k(const int* __restrict__ counts, int* __restrict__ offs){
  const int T = 1024;
  int t = threadIdx.x;
  int chunk = (NN + T - 1) / T;
  int lo = t*chunk;
  int hi = lo + chunk; if(hi > NN) hi = NN;
  int s = 0;
  for(int i=lo;i<hi;i++) s += counts[i];
  __shared__ int sm[T];
  sm[t] = s; __syncthreads();
  for(int off=1; off<T; off<<=1){
    int v = (t >= off) ? sm[t-off] : 0;
    __syncthreads();
    sm[t] += v;
    __syncthreads();
  }
  int run = sm[t] - s;
  for(int i=lo;i<hi;i++){ offs[i] = run; run += counts[i]; }
  if(t == T-1) offs[NN] = run;
}

__global__ __launch_bounds__(256) void scatter_k(const int* __restrict__ src, const int* __restrict__ offs,
                                                 int* __restrict__ cursor, int* __restrict__ perm){
  int e = blockIdx.x*blockDim.x + threadIdx.x;
  if(e < EE){
    int s = src[e];
    if((unsigned)s >= NN) s = 0;
    int pos = offs[s] + atomicAdd(&cursor[s], 1);
    perm[pos] = e;
  }
}

// ---------------- prep: tgt in CSR order ----------------
__global__ __launch_bounds__(256) void prep_k(const int* __restrict__ perm, const int* __restrict__ tgt,
                                              int* __restrict__ tgt_s){
  int i = blockIdx.x*blockDim.x + threadIdx.x;
  if(i < EE){
    int t = tgt[perm[i]];
    if((unsigned)t >= NN) t = 0;
    tgt_s[i] = t;
  }
}

// ---- edge MLP + 9 a_edge dots, input gathered via perm, q written CSR-ordered ----
__global__ __launch_bounds__(256) void edge_mlp_q(const int* __restrict__ perm, const float* __restrict__ ea,
                                                  const float* __restrict__ w, const float* __restrict__ b,
                                                  const float* __restrict__ g, const float* __restrict__ beta,
                                                  const float* __restrict__ gat_a, const float* __restrict__ out_a,
                                                  float* __restrict__ q){
  int i = blockIdx.x*blockDim.x + threadIdx.x;
  if(i >= EE) return;
  int pe = perm[i];
  float in[8];
#pragma unroll
  for(int k=0;k<8;k++) in[k] = ea[(size_t)pe*8 + k];
  float y[64];
#pragma unroll
  for(int j=0;j<64;j++){
    float acc = b[j];
#pragma unroll
    for(int k=0;k<8;k++) acc += in[k] * w[k*64+j];
    y[j] = acc;
  }
  float mu = 0.f;
#pragma unroll
  for(int j=0;j<64;j++) mu += y[j];
  mu *= (1.0f/64.0f);
  float var = 0.f;
#pragma unroll
  for(int j=0;j<64;j++){ float d = y[j]-mu; var += d*d; }
  var *= (1.0f/64.0f);
  float inv = rsqrtf(var + 1e-5f);
#pragma unroll
  for(int j=0;j<64;j++) y[j] = fmaxf((y[j]-mu)*inv*g[j] + beta[j], 0.0f);
#pragma unroll
  for(int r=0;r<9;r++){
    const float* av = (r<8) ? (gat_a + r*192 + 128) : (out_a + 128);
    float d = 0.f;
#pragma unroll
    for(int j=0;j<64;j++) d += y[j]*av[j];
    q[(size_t)r*EE + i] = d;
  }
}

// ---------------- per-head projection: H = x@W, p_src, p_tgt ----------------
__global__ __launch_bounds__(256) void project(const float* __restrict__ x, const float* __restrict__ W,
                                               const float* __restrict__ a, float* __restrict__ H,
                                               float* __restrict__ psrc, float* __restrict__ ptgt){
  int wid  = (blockIdx.x*blockDim.x + threadIdx.x) >> 6;
  int lane = threadIdx.x & 63;
  if(wid >= NN) return;
  float xv = x[(size_t)wid*64 + lane];
  float acc = 0.f;
#pragma unroll
  for(int k=0;k<64;k++){
    acc += __shfl(xv, k, 64) * W[k*64+lane];
  }
  H[(size_t)wid*64 + lane] = acc;
  float ps = wsum(acc * a[lane]);
  float pt = wsum(acc * a[64+lane]);
  if(lane == 0){ psrc[wid] = ps; ptgt[wid] = pt; }
}

// ---- per-head edge score prefix: s_s[i] = ptgt[tgt_s[i]] + q_h[i] (no psrc, no lrelu) ----
__global__ __launch_bounds__(256) void score_k(const int* __restrict__ tgt_s, const float* __restrict__ ptgt,
                                               const float* __restrict__ qh, float* __restrict__ s_s){
  int i = blockIdx.x*blockDim.x + threadIdx.x;
  if(i < EE) s_s[i] = ptgt[tgt_s[i]] + qh[i];
}

// ---- per-head aggregation (quad-split, two-pass max) + fused out_W GEMV into h2f ----
__global__ __launch_bounds__(256) void aggregate_head(const int* __restrict__ offs, const int* __restrict__ tgt_s,
                                                      const float* __restrict__ psrc, const float* __restrict__ s_s,
                                                      const float* __restrict__ H, const float* __restrict__ outW,
                                                      int h, float* __restrict__ h2f){
  int wid  = (blockIdx.x*blockDim.x + threadIdx.x) >> 6;
  int lane = threadIdx.x & 63;
  if(wid >= NN) return;
  int quad = lane >> 4, l16 = lane & 15;
  int b  = offs[wid];
  int e2 = offs[wid+1];
  float ps = psrc[wid];
  // pass A: per-node max of leaky_relu scores
  float m = -3.0e38f;
  for(int i=b+quad; i<e2; i+=4){
    float s = ps + s_s[i];
    s = (s > 0.f) ? s : 0.01f*s;
    m = fmaxf(m, s);
  }
  m = fmaxf(m, __shfl_xor(m,16,64));
  m = fmaxf(m, __shfl_xor(m,32,64));
  // pass B: exp + weighted H gather (float4 per 16 lanes, 4 edges in flight)
  const float4* H4 = (const float4*)H;
  float4 num = make_float4(0.f,0.f,0.f,0.f);
  float den = 0.f;
  for(int i=b+quad; i<e2; i+=4){
    int t = tgt_s[i];
    float s = ps + s_s[i];
    s = (s > 0.f) ? s : 0.01f*s;
    float w = __expf(s - m);
    den += w;
    float4 hv = H4[(size_t)t*16 + l16];
    num.x += w*hv.x; num.y += w*hv.y; num.z += w*hv.z; num.w += w*hv.w;
  }
  den   += __shfl_xor(den,16,64);   den   += __shfl_xor(den,32,64);
  num.x += __shfl_xor(num.x,16,64); num.x += __shfl_xor(num.x,32,64);
  num.y += __shfl_xor(num.y,16,64); num.y += __shfl_xor(num.y,32,64);
  num.z += __shfl_xor(num.z,16,64); num.z += __shfl_xor(num.z,32,64);
  num.w += __shfl_xor(num.w,16,64); num.w += __shfl_xor(num.w,32,64);
  float inv = (den > 0.f) ? 1.0f/den : 0.f;
  float z2[4];
#pragma unroll
  for(int k=0;k<4;k++){
    float hp = ((&num.x)[k]) * inv;
    float z  = (hp > 0.f) ? hp : expm1f(hp);   // elu (gat_layer output)
    z2[k]    = (z  > 0.f) ? z  : expm1f(z);    // elu (xh = elu(concat))
  }
  // fused GEMV: h2 += z2_row @ out_W[h*64:(h+1)*64, :]  (column owned: lane)
  float acc = 0.f;
#pragma unroll
  for(int j=0;j<64;j++){
    float zj = __shfl(z2[j&3], j>>2, 64);      // lane j>>2 holds column j in comp j&3
    acc += zj * outW[(size_t)(h*64+j)*64 + lane];
  }
  h2f[(size_t)wid*64 + lane] += acc;
}

// ---- finalize: p2 from h2f, h2 copied into H buffer ----
__global__ __launch_bounds__(256) void finalize_k(const float* __restrict__ h2f, const float* __restrict__ out_a,
                                                  float* __restrict__ H, float* __restrict__ psrc,
                                                  float* __restrict__ ptgt){
  int wid  = (blockIdx.x*blockDim.x + threadIdx.x) >> 6;
  int lane = threadIdx.x & 63;
  if(wid >= NN) return;
  float v = h2f[(size_t)wid*64 + lane];
  float ps = wsum(v * out_a[lane]);
  float pt = wsum(v * out_a[64+lane]);
  if(lane == 0){ psrc[wid] = ps; ptgt[wid] = pt; }
  H[(size_t)wid*64 + lane] = v;
}

// ---- output layer aggregation + log_softmax -> dout ----
__global__ __launch_bounds__(256) void aggregate_out(const int* __restrict__ offs, const int* __restrict__ tgt_s,
                                                     const float* __restrict__ psrc, const float* __restrict__ s_s,
                                                     const float* __restrict__ H, float* __restrict__ dout){
  int wid  = (blockIdx.x*blockDim.x + threadIdx.x) >> 6;
  int lane = threadIdx.x & 63;
  if(wid >= NN) return;
  int quad = lane >> 4, l16 = lane & 15;
  int b  = offs[wid];
  int e2 = offs[wid+1];
  float ps = psrc[wid];
  float m = -3.0e38f;
  for(int i=b+quad; i<e2; i+=4){
    float s = ps + s_s[i];
    s = (s > 0.f) ? s : 0.01f*s;
    m = fmaxf(m, s);
  }
  m = fmaxf(m, __shfl_xor(m,16,64));
  m = fmaxf(m, __shfl_xor(m,32,64));
  const float4* H4 = (const float4*)H;
  float4 num = make_float4(0.f,0.f,0.f,0.f);
  float den = 0.f;
  for(int i=b+quad; i<e2; i+=4){
    int t = tgt_s[i];
    float s = ps + s_s[i];
    s = (s > 0.f) ? s : 0.01f*s;
    float w = __expf(s - m);
    den += w;
    float4 hv = H4[(size_t)t*16 + l16];
    num.x += w*hv.x; num.y += w*hv.y; num.z += w*hv.z; num.w += w*hv.w;
  }
  den   += __shfl_xor(den,16,64);   den   += __shfl_xor(den,32,64);
  num.x += __shfl_xor(num.x,16,64); num.x += __shfl_xor(num.x,32,64);
  num.y += __shfl_xor(num.y,16,64); num.y += __shfl_xor(num.y,32,64);
  num.z += __shfl_xor(num.z,16,64); num.z += __shfl_xor(num.z,32,64);
  num.w += __shfl_xor(num.w,16,64); num.w += __shfl_xor(num.w,32,64);
  float inv = (den > 0.f) ? 1.0f/den : 0.f;
  float z[4];
  float mloc = -3.0e38f;
#pragma unroll
  for(int k=0;k<4;k++){
    float hp = ((&num.x)[k]) * inv;
    z[k] = (hp > 0.f) ? hp : expm1f(hp);       // elu
    mloc = fmaxf(mloc, z[k]);
  }
  // log_softmax over the 64 columns: reduce across the 16 lanes of each quad
#pragma unroll
  for(int msk=1; msk<16; msk<<=1) mloc = fmaxf(mloc, __shfl_xor(mloc,msk,64));
  float ssum = 0.f;
#pragma unroll
  for(int k=0;k<4;k++) ssum += __expf(z[k] - mloc);
#pragma unroll
  for(int msk=1; msk<16; msk<<=1) ssum += __shfl_xor(ssum,msk,64);
  float lse = mloc + logf(ssum);
  if(quad == 0){
    float4 o = make_float4(z[0]-lse, z[1]-lse, z[2]-lse, z[3]-lse);
    ((float4*)dout)[(size_t)wid*16 + l16] = o;
  }
}

extern "C" void kernel_launch(void* const* d_in, const int* in_sizes, int n_in,
                              void* d_out, int out_size, void* d_ws, size_t ws_size,
                              hipStream_t stream) {
  const float* X         = (const float*)d_in[0];
  const float* edge_attr = (const float*)d_in[1];
  const int*   edge_index= (const int*)d_in[2];
  const float* w_node    = (const float*)d_in[4];
  const float* b_node    = (const float*)d_in[5];
  const float* g_node    = (const float*)d_in[6];
  const float* beta_node = (const float*)d_in[7];
  const float* w_edge    = (const float*)d_in[8];
  const float* b_edge    = (const float*)d_in[9];
  const float* g_edge    = (const float*)d_in[10];
  const float* beta_edge = (const float*)d_in[11];
  const float* gat_W     = (const float*)d_in[12];
  const float* gat_a     = (const float*)d_in[13];
  const float* out_W     = (const float*)d_in[14];
  const float* out_a     = (const float*)d_in[15];
  float* dout = (float*)d_out;

  const int* src = edge_index;
  const int* tgt = edge_index + EE;

  // ---- workspace layout: control arrays first (bytes, 16B aligned); ~87.5 MB ----
  char* base = (char*)d_ws;
  size_t off = 0;
  auto take = [&](size_t bytes)->char*{ char* p = base + off; off += (bytes + 15) & ~(size_t)15; return p; };
  int*    counts = (int*)  take((size_t)NN*4);
  int*    cursor = (int*)  take((size_t)NN*4);
  int*    offs   = (int*)  take((size_t)(NN+1)*4);
  float*  psrc   = (float*)take((size_t)NN*4);
  float*  ptgt   = (float*)take((size_t)NN*4);
  int*    perm   = (int*)  take((size_t)EE*4);
  int*    tgt_s  = (int*)  take((size_t)EE*4);
  float*  s_s    = (float*)take((size_t)EE*4);
  float*  h2f    = (float*)take((size_t)NN*64*4);
  float*  x      = (float*)take((size_t)NN*64*4);
  float*  H      = (float*)take((size_t)NN*64*4);
  float*  q      = (float*)take((size_t)9*EE*4);

  const int NBLK_N  = (NN*64 + 255)/256;   // wave-per-node kernels: 12500
  const int NBLK_E  = (EE + 255)/256;      // thread-per-edge kernels: 3907

  zero_k<<<NBLK_N, 256, 0, stream>>>(counts, cursor, h2f);
  node_mlp<<<NBLK_N, 256, 0, stream>>>(X, w_node, b_node, g_node, beta_node, x);
  hist_k<<<NBLK_E, 256, 0, stream>>>(src, counts);
  scan_k<<<1, 1024, 0, stream>>>(counts, offs);
  scatter_k<<<NBLK_E, 256, 0, stream>>>(src, offs, cursor, perm);
  prep_k<<<NBLK_E, 256, 0, stream>>>(perm, tgt, tgt_s);
  edge_mlp_q<<<NBLK_E, 256, 0, stream>>>(perm, edge_attr, w_edge, b_edge, g_edge, beta_edge,
                                         gat_a, out_a, q);

  for(int h=0; h<8; h++){
    project<<<NBLK_N, 256, 0, stream>>>(x, gat_W + (size_t)h*64*64, gat_a + (size_t)h*192, H, psrc, ptgt);
    score_k<<<NBLK_E, 256, 0, stream>>>(tgt_s, ptgt, q + (size_t)h*EE, s_s);
    aggregate_head<<<NBLK_N, 256, 0, stream>>>(offs, tgt_s, psrc, s_s, H, out_W, h, h2f);
  }

  finalize_k<<<NBLK_N, 256, 0, stream>>>(h2f, out_a, H, psrc, ptgt);
  score_k<<<NBLK_E, 256, 0, stream>>>(tgt_s, ptgt, q + (size_t)8*EE, s_s);
  aggregate_out<<<NBLK_N, 256, 0, stream>>>(offs, tgt_s, psrc, s_s, H, dout);
}

// Round 5
// 1022.122 us; speedup vs baseline: 2.1490x; 1.3528x over previous
//
#include <hip/hip_runtime.h>

#define NN 50000
#define EE 1000000

__device__ __forceinline__ float wsum(float v){
#pragma unroll
  for(int m=1;m<64;m<<=1) v += __shfl_xor(v,m,64);
  return v;
}

// ---------------- zero counts/cursor ----------------
__global__ __launch_bounds__(256) void zero_k(int* counts, int* cursor){
  int i = blockIdx.x*blockDim.x + threadIdx.x;
  if(i < NN){ counts[i] = 0; cursor[i] = 0; }
}

// ---------------- node MLP: x = relu(LN(X@w + b)) ----------------
__global__ __launch_bounds__(256) void node_mlp(const float* __restrict__ X, const float* __restrict__ w,
                                                const float* __restrict__ b, const float* __restrict__ g,
                                                const float* __restrict__ beta, float* __restrict__ x){
  int wid  = (blockIdx.x*blockDim.x + threadIdx.x) >> 6;
  int lane = threadIdx.x & 63;
  if(wid >= NN) return;
  float acc = b[lane];
#pragma unroll
  for(int k=0;k<16;k++) acc += X[wid*16+k] * w[k*64+lane];
  float mu  = wsum(acc) * (1.0f/64.0f);
  float d   = acc - mu;
  float var = wsum(d*d) * (1.0f/64.0f);
  float y   = d * rsqrtf(var + 1e-5f) * g[lane] + beta[lane];
  x[(size_t)wid*64 + lane] = fmaxf(y, 0.0f);
}

// ---------------- CSR build ----------------
__global__ __launch_bounds__(256) void hist_k(const int* __restrict__ src, int* __restrict__ counts){
  int e = blockIdx.x*blockDim.x + threadIdx.x;
  if(e < EE){
    int s = src[e];
    if((unsigned)s >= NN) s = 0;
    atomicAdd(&counts[s], 1);
  }
}

// 3-kernel parallel scan (replaces 77us single-block scan_k)
__global__ __launch_bounds__(256) void scan1_k(const int* __restrict__ counts, int* __restrict__ bsum){
  int i = blockIdx.x*256 + threadIdx.x;
  int v = (i < NN) ? counts[i] : 0;
  int s = v;
#pragma unroll
  for(int m=1;m<64;m<<=1) s += __shfl_xor(s,m,64);
  __shared__ int sm[4];
  if((threadIdx.x & 63) == 0) sm[threadIdx.x>>6] = s;
  __syncthreads();
  if(threadIdx.x == 0) bsum[blockIdx.x] = sm[0]+sm[1]+sm[2]+sm[3];
}

__global__ __launch_bounds__(256) void scan2_k(const int* __restrict__ bsum, int* __restrict__ bpre,
                                               int* __restrict__ offs){
  const int NB = (NN + 255)/256;
  int t = threadIdx.x;
  __shared__ int sm[256];
  int v = (t < NB) ? bsum[t] : 0;
  sm[t] = v; __syncthreads();
  for(int off=1; off<256; off<<=1){
    int u = (t >= off) ? sm[t-off] : 0;
    __syncthreads();
    sm[t] += u;
    __syncthreads();
  }
  if(t < NB) bpre[t] = sm[t] - v;
  if(t == 0) offs[NN] = EE;
}

__global__ __launch_bounds__(256) void scan3_k(const int* __restrict__ counts, const int* __restrict__ bpre,
                                               int* __restrict__ offs){
  int i = blockIdx.x*256 + threadIdx.x;
  int t = threadIdx.x;
  __shared__ int sm[256];
  int v = (i < NN) ? counts[i] : 0;
  sm[t] = v; __syncthreads();
  for(int off=1; off<256; off<<=1){
    int u = (t >= off) ? sm[t-off] : 0;
    __syncthreads();
    sm[t] += u;
    __syncthreads();
  }
  if(i < NN) offs[i] = bpre[blockIdx.x] + sm[t] - v;
}

__global__ __launch_bounds__(256) void scatter_k(const int* __restrict__ src, const int* __restrict__ offs,
                                                 int* __restrict__ cursor, int* __restrict__ perm){
  int e = blockIdx.x*blockDim.x + threadIdx.x;
  if(e < EE){
    int s = src[e];
    if((unsigned)s >= NN) s = 0;
    int pos = offs[s] + atomicAdd(&cursor[s], 1);
    perm[pos] = e;
  }
}

// ---------------- prep: tgt in CSR order ----------------
__global__ __launch_bounds__(256) void prep_k(const int* __restrict__ perm, const int* __restrict__ tgt,
                                              int* __restrict__ tgt_s){
  int i = blockIdx.x*blockDim.x + threadIdx.x;
  if(i < EE){
    int t = tgt[perm[i]];
    if((unsigned)t >= NN) t = 0;
    tgt_s[i] = t;
  }
}

// ---- edge MLP + 9 a_edge dots, input via perm; q8 [E][8] interleaved, q_out [E] ----
__global__ __launch_bounds__(256) void edge_mlp_q(const int* __restrict__ perm, const float* __restrict__ ea,
                                                  const float* __restrict__ w, const float* __restrict__ b,
                                                  const float* __restrict__ g, const float* __restrict__ beta,
                                                  const float* __restrict__ gat_a, const float* __restrict__ out_a,
                                                  float* __restrict__ q8, float* __restrict__ q_out){
  int i = blockIdx.x*blockDim.x + threadIdx.x;
  if(i >= EE) return;
  int pe = perm[i];
  float in[8];
#pragma unroll
  for(int k=0;k<8;k++) in[k] = ea[(size_t)pe*8 + k];
  float y[64];
#pragma unroll
  for(int j=0;j<64;j++){
    float acc = b[j];
#pragma unroll
    for(int k=0;k<8;k++) acc += in[k] * w[k*64+j];
    y[j] = acc;
  }
  float mu = 0.f;
#pragma unroll
  for(int j=0;j<64;j++) mu += y[j];
  mu *= (1.0f/64.0f);
  float var = 0.f;
#pragma unroll
  for(int j=0;j<64;j++){ float d = y[j]-mu; var += d*d; }
  var *= (1.0f/64.0f);
  float inv = rsqrtf(var + 1e-5f);
#pragma unroll
  for(int j=0;j<64;j++) y[j] = fmaxf((y[j]-mu)*inv*g[j] + beta[j], 0.0f);
#pragma unroll
  for(int r=0;r<8;r++){
    const float* av = gat_a + r*192 + 128;
    float d = 0.f;
#pragma unroll
    for(int j=0;j<64;j++) d += y[j]*av[j];
    q8[(size_t)i*8 + r] = d;
  }
  {
    const float* av = out_a + 128;
    float d = 0.f;
#pragma unroll
    for(int j=0;j<64;j++) d += y[j]*av[j];
    q_out[i] = d;
  }
}

// ---- cvec: c_src[h] = W_h @ a_src_h, c_tgt[h] = W_h @ a_tgt_h ----
__global__ __launch_bounds__(64) void cvec_k(const float* __restrict__ gat_W, const float* __restrict__ gat_a,
                                             float* __restrict__ cdir){
  int h = blockIdx.x, k = threadIdx.x;
  const float* W = gat_W + (size_t)h*64*64;
  const float* a = gat_a + (size_t)h*192;
  float cs = 0.f, ct = 0.f;
#pragma unroll
  for(int j=0;j<64;j++){ float wv = W[k*64+j]; cs += wv*a[j]; ct += wv*a[64+j]; }
  cdir[h*64 + k]       = cs;
  cdir[512 + h*64 + k] = ct;
}

// ---- pq: ps8[n][h] = x_n . c_src[h], pt8[n][h] = x_n . c_tgt[h] ----
__global__ __launch_bounds__(256) void pq_k(const float* __restrict__ x, const float* __restrict__ cdir,
                                            float* __restrict__ ps8, float* __restrict__ pt8){
  int wid  = (blockIdx.x*blockDim.x + threadIdx.x) >> 6;
  int lane = threadIdx.x & 63;
  if(wid >= NN) return;
  float xv = x[(size_t)wid*64 + lane];
#pragma unroll 1
  for(int h=0;h<8;h++){
    float a = wsum(xv * cdir[h*64+lane]);
    float c = wsum(xv * cdir[512 + h*64+lane]);
    if(lane == 0){ ps8[wid*8+h] = a; pt8[wid*8+h] = c; }
  }
}

// ---- mega aggregate: all 8 heads share one x[t] gather; per-node 8x(64x64) matvec,
//      double-ELU, fused out_W GEMV -> h2f, plus out-layer p-scalars ----
__global__ __launch_bounds__(256) void mega_agg(const int* __restrict__ offs, const int* __restrict__ tgt_s,
    const float* __restrict__ ps8, const float* __restrict__ pt8, const float* __restrict__ q8,
    const float* __restrict__ x, const float* __restrict__ gat_W, const float* __restrict__ outW,
    const float* __restrict__ out_a, float* __restrict__ h2f, float* __restrict__ ps_o,
    float* __restrict__ pt_o){
  __shared__ float pre[4][512];
  int wid  = (blockIdx.x*blockDim.x + threadIdx.x) >> 6;
  int lane = threadIdx.x & 63;
  int wv   = threadIdx.x >> 6;
  if(wid >= NN) return;               // never taken: 12500 blocks x 4 waves == NN exactly
  int quad = lane >> 4, l16 = lane & 15;
  int b  = offs[wid];
  int e2 = offs[wid+1];
  float ps[8];
#pragma unroll
  for(int h=0;h<8;h++) ps[h] = ps8[wid*8+h];
  // pass A: per-head per-node max of leaky_relu scores
  float m[8];
#pragma unroll
  for(int h=0;h<8;h++) m[h] = -3.0e38f;
  for(int i=b+quad; i<e2; i+=4){
    int t = tgt_s[i];
    const float4* qp = (const float4*)(q8 + (size_t)i*8);
    const float4* pp = (const float4*)(pt8 + (size_t)t*8);
    float4 qa = qp[0], qb = qp[1], pa = pp[0], pb = pp[1];
    float sv[8] = {qa.x+pa.x, qa.y+pa.y, qa.z+pa.z, qa.w+pa.w,
                   qb.x+pb.x, qb.y+pb.y, qb.z+pb.z, qb.w+pb.w};
#pragma unroll
    for(int h=0;h<8;h++){
      float s = ps[h] + sv[h];
      s = (s > 0.f) ? s : 0.01f*s;
      m[h] = fmaxf(m[h], s);
    }
  }
#pragma unroll
  for(int h=0;h<8;h++){
    m[h] = fmaxf(m[h], __shfl_xor(m[h],16,64));
    m[h] = fmaxf(m[h], __shfl_xor(m[h],32,64));
  }
  // pass B: shared x[t] gather, 8 weighted accumulations
  float  den[8];
  float4 num[8];
#pragma unroll
  for(int h=0;h<8;h++){ den[h] = 0.f; num[h] = make_float4(0.f,0.f,0.f,0.f); }
  const float4* X4 = (const float4*)x;
  for(int i=b+quad; i<e2; i+=4){
    int t = tgt_s[i];
    const float4* qp = (const float4*)(q8 + (size_t)i*8);
    const float4* pp = (const float4*)(pt8 + (size_t)t*8);
    float4 qa = qp[0], qb = qp[1], pa = pp[0], pb = pp[1];
    float4 xv = X4[(size_t)t*16 + l16];
    float sv[8] = {qa.x+pa.x, qa.y+pa.y, qa.z+pa.z, qa.w+pa.w,
                   qb.x+pb.x, qb.y+pb.y, qb.z+pb.z, qb.w+pb.w};
#pragma unroll
    for(int h=0;h<8;h++){
      float s = ps[h] + sv[h];
      s = (s > 0.f) ? s : 0.01f*s;
      float w = __expf(s - m[h]);
      den[h]   += w;
      num[h].x += w*xv.x; num[h].y += w*xv.y; num[h].z += w*xv.z; num[h].w += w*xv.w;
    }
  }
#pragma unroll
  for(int h=0;h<8;h++){
    den[h]   += __shfl_xor(den[h],16,64);   den[h]   += __shfl_xor(den[h],32,64);
    num[h].x += __shfl_xor(num[h].x,16,64); num[h].x += __shfl_xor(num[h].x,32,64);
    num[h].y += __shfl_xor(num[h].y,16,64); num[h].y += __shfl_xor(num[h].y,32,64);
    num[h].z += __shfl_xor(num[h].z,16,64); num[h].z += __shfl_xor(num[h].z,32,64);
    num[h].w += __shfl_xor(num[h].w,16,64); num[h].w += __shfl_xor(num[h].w,32,64);
  }
  // stage normalized pre-features in LDS (quad 0 holds all 64 comps)
  if(quad == 0){
#pragma unroll
    for(int h=0;h<8;h++){
      float invd = (den[h] > 0.f) ? 1.0f/den[h] : 0.f;
      pre[wv][h*64 + l16*4 + 0] = num[h].x*invd;
      pre[wv][h*64 + l16*4 + 1] = num[h].y*invd;
      pre[wv][h*64 + l16*4 + 2] = num[h].z*invd;
      pre[wv][h*64 + l16*4 + 3] = num[h].w*invd;
    }
  }
  __syncthreads();   // all 4 waves alive (no tail); orders LDS write->read
  // per-node transform: v^h = pre^h @ W_h, double-ELU, fused out_W GEMV
  float outacc = 0.f;
#pragma unroll 1
  for(int h=0;h<8;h++){
    const float* W = gat_W + (size_t)h*4096;
    float v = 0.f;
    for(int j=0;j<64;j++) v += pre[wv][h*64+j] * W[j*64+lane];
    float z  = (v > 0.f) ? v : expm1f(v);   // elu (gat_layer)
    float z2 = (z > 0.f) ? z : expm1f(z);   // elu (xh)
    const float* OW = outW + (size_t)h*64*64;
    for(int j=0;j<64;j++) outacc += __shfl(z2, j, 64) * OW[j*64+lane];
  }
  h2f[(size_t)wid*64 + lane] = outacc;
  float pso = wsum(outacc * out_a[lane]);
  float pto = wsum(outacc * out_a[64+lane]);
  if(lane == 0){ ps_o[wid] = pso; pt_o[wid] = pto; }
}

// ---- output layer aggregation + log_softmax -> dout ----
__global__ __launch_bounds__(256) void agg_out(const int* __restrict__ offs, const int* __restrict__ tgt_s,
                                               const float* __restrict__ ps_o, const float* __restrict__ pt_o,
                                               const float* __restrict__ q_out, const float* __restrict__ h2f,
                                               float* __restrict__ dout){
  int wid  = (blockIdx.x*blockDim.x + threadIdx.x) >> 6;
  int lane = threadIdx.x & 63;
  if(wid >= NN) return;
  int quad = lane >> 4, l16 = lane & 15;
  int b  = offs[wid];
  int e2 = offs[wid+1];
  float ps = ps_o[wid];
  float m = -3.0e38f;
  for(int i=b+quad; i<e2; i+=4){
    float s = ps + pt_o[tgt_s[i]] + q_out[i];
    s = (s > 0.f) ? s : 0.01f*s;
    m = fmaxf(m, s);
  }
  m = fmaxf(m, __shfl_xor(m,16,64));
  m = fmaxf(m, __shfl_xor(m,32,64));
  const float4* H4 = (const float4*)h2f;
  float4 num = make_float4(0.f,0.f,0.f,0.f);
  float den = 0.f;
  for(int i=b+quad; i<e2; i+=4){
    int t = tgt_s[i];
    float s = ps + pt_o[t] + q_out[i];
    s = (s > 0.f) ? s : 0.01f*s;
    float w = __expf(s - m);
    den += w;
    float4 hv = H4[(size_t)t*16 + l16];
    num.x += w*hv.x; num.y += w*hv.y; num.z += w*hv.z; num.w += w*hv.w;
  }
  den   += __shfl_xor(den,16,64);   den   += __shfl_xor(den,32,64);
  num.x += __shfl_xor(num.x,16,64); num.x += __shfl_xor(num.x,32,64);
  num.y += __shfl_xor(num.y,16,64); num.y += __shfl_xor(num.y,32,64);
  num.z += __shfl_xor(num.z,16,64); num.z += __shfl_xor(num.z,32,64);
  num.w += __shfl_xor(num.w,16,64); num.w += __shfl_xor(num.w,32,64);
  float inv = (den > 0.f) ? 1.0f/den : 0.f;
  float z[4];
  float mloc = -3.0e38f;
#pragma unroll
  for(int k=0;k<4;k++){
    float hp = ((&num.x)[k]) * inv;
    z[k] = (hp > 0.f) ? hp : expm1f(hp);
    mloc = fmaxf(mloc, z[k]);
  }
#pragma unroll
  for(int msk=1; msk<16; msk<<=1) mloc = fmaxf(mloc, __shfl_xor(mloc,msk,64));
  float ssum = 0.f;
#pragma unroll
  for(int k=0;k<4;k++) ssum += __expf(z[k] - mloc);
#pragma unroll
  for(int msk=1; msk<16; msk<<=1) ssum += __shfl_xor(ssum,msk,64);
  float lse = mloc + logf(ssum);
  if(quad == 0){
    float4 o = make_float4(z[0]-lse, z[1]-lse, z[2]-lse, z[3]-lse);
    ((float4*)dout)[(size_t)wid*16 + l16] = o;
  }
}

extern "C" void kernel_launch(void* const* d_in, const int* in_sizes, int n_in,
                              void* d_out, int out_size, void* d_ws, size_t ws_size,
                              hipStream_t stream) {
  const float* X         = (const float*)d_in[0];
  const float* edge_attr = (const float*)d_in[1];
  const int*   edge_index= (const int*)d_in[2];
  const float* w_node    = (const float*)d_in[4];
  const float* b_node    = (const float*)d_in[5];
  const float* g_node    = (const float*)d_in[6];
  const float* beta_node = (const float*)d_in[7];
  const float* w_edge    = (const float*)d_in[8];
  const float* b_edge    = (const float*)d_in[9];
  const float* g_edge    = (const float*)d_in[10];
  const float* beta_edge = (const float*)d_in[11];
  const float* gat_W     = (const float*)d_in[12];
  const float* gat_a     = (const float*)d_in[13];
  const float* out_W     = (const float*)d_in[14];
  const float* out_a     = (const float*)d_in[15];
  float* dout = (float*)d_out;

  const int* src = edge_index;
  const int* tgt = edge_index + EE;

  // ---- workspace (~74 MB), control arrays first, 32B-aligned ----
  char* base = (char*)d_ws;
  size_t off = 0;
  auto take = [&](size_t bytes)->char*{ char* p = base + off; off += (bytes + 31) & ~(size_t)31; return p; };
  int*    counts = (int*)  take((size_t)NN*4);
  int*    cursor = (int*)  take((size_t)NN*4);
  int*    offs   = (int*)  take((size_t)(NN+1)*4);
  int*    bsum   = (int*)  take(256*4);
  int*    bpre   = (int*)  take(256*4);
  float*  ps_o   = (float*)take((size_t)NN*4);
  float*  pt_o   = (float*)take((size_t)NN*4);
  float*  cdir   = (float*)take(1024*4);
  int*    perm   = (int*)  take((size_t)EE*4);
  int*    tgt_s  = (int*)  take((size_t)EE*4);
  float*  ps8    = (float*)take((size_t)NN*8*4);
  float*  pt8    = (float*)take((size_t)NN*8*4);
  float*  x      = (float*)take((size_t)NN*64*4);
  float*  h2f    = (float*)take((size_t)NN*64*4);
  float*  q8     = (float*)take((size_t)EE*8*4);
  float*  q_out  = (float*)take((size_t)EE*4);

  const int NBLK_N  = (NN*64 + 255)/256;   // wave-per-node kernels: 12500
  const int NBLK_E  = (EE + 255)/256;      // thread-per-edge kernels: 3907
  const int NBLK_S  = (NN + 255)/256;      // 196

  zero_k  <<<NBLK_S, 256, 0, stream>>>(counts, cursor);
  node_mlp<<<NBLK_N, 256, 0, stream>>>(X, w_node, b_node, g_node, beta_node, x);
  hist_k  <<<NBLK_E, 256, 0, stream>>>(src, counts);
  scan1_k <<<NBLK_S, 256, 0, stream>>>(counts, bsum);
  scan2_k <<<1,      256, 0, stream>>>(bsum, bpre, offs);
  scan3_k <<<NBLK_S, 256, 0, stream>>>(counts, bpre, offs);
  scatter_k<<<NBLK_E,256, 0, stream>>>(src, offs, cursor, perm);
  prep_k  <<<NBLK_E, 256, 0, stream>>>(perm, tgt, tgt_s);
  edge_mlp_q<<<NBLK_E,256,0, stream>>>(perm, edge_attr, w_edge, b_edge, g_edge, beta_edge,
                                       gat_a, out_a, q8, q_out);
  cvec_k  <<<8,       64, 0, stream>>>(gat_W, gat_a, cdir);
  pq_k    <<<NBLK_N, 256, 0, stream>>>(x, cdir, ps8, pt8);
  mega_agg<<<NBLK_N, 256, 0, stream>>>(offs, tgt_s, ps8, pt8, q8, x, gat_W, out_W, out_a,
                                       h2f, ps_o, pt_o);
  agg_out <<<NBLK_N, 256, 0, stream>>>(offs, tgt_s, ps_o, pt_o, q_out, h2f, dout);
}